// Round 8
// baseline (117.484 us; speedup 1.0000x reference)
//
#include <hip/hip_runtime.h>
#include <hip/hip_bf16.h>
#include <math.h>

// Problem constants
constexpr int B  = 2;
constexpr int C  = 64;
constexpr int H  = 128;
constexpr int W  = 128;
constexpr int O  = 64;
constexpr int DG = 8;
constexpr int K  = 3;
constexpr int KK = K * K;           // 9
constexpr int HW = H * W;           // 16384
constexpr int CG = C / DG;          // 8
constexpr int OM_C  = 3 * DG * KK;  // 216
constexpr int OFF_C = 2 * DG * KK;  // 144
constexpr int MSK_C = DG * KK;      // 72
constexpr float MRM = 10.0f;

typedef unsigned short u16;
typedef short bfx8 __attribute__((ext_vector_type(8)));   // 8 bf16 (4 VGPRs)
typedef float fx4 __attribute__((ext_vector_type(4)));    // MFMA accumulator

// Sizes
constexpr int WT_N   = 576 * 64;        // deform weights, transposed
constexpr int X0T_N  = B * C * HW;      // 2097152 floats (x0 interleaved)
constexpr int STEP_E = 14336;           // u16 per tc-step: 14 nfh x 2 wsel x 64 x 8
constexpr int WB_N   = 18 * STEP_E;     // 258048

// XCD chunk swizzle (512 blocks): XCD x gets 64 consecutive works.
__device__ __forceinline__ int xcd_work(int bid) {
    return ((bid & 7) << 6) + (bid >> 3);
}

// ---------------- prep1: wT (deform), x1T hi/lo (pixel-major bf16), wB ----
// wB layout (u16): [step 18][nfh 14][wsel 2][lane 64][j 8]
//   step = t*2+chunk; ic = chunk*32 + (lane>>4)*8 + j; oc = nfh*16 + (lane&15)
__global__ void __launch_bounds__(256)
prep1_kernel(const float* __restrict__ weight,
             const float* __restrict__ w_om,
             const float* __restrict__ x1,
             float* __restrict__ wT,
             u16* __restrict__ x1T_hi,
             u16* __restrict__ x1T_lo,
             u16* __restrict__ wB) {
    int idx = blockIdx.x * 256 + threadIdx.x;
    if (idx < WT_N) {
        int r = idx / O;          // (g*KK+i)*CG + c
        int o = idx - r * O;
        int g = r / (KK * CG);
        int rem = r - g * (KK * CG);
        int i = rem / CG;
        int c = rem - i * CG;
        wT[idx] = weight[o * (C * KK) + (g * CG + c) * KK + i];
        return;
    }
    int i1 = idx - WT_N;
    if (i1 < B * HW) {   // one thread per (b,p): transpose x1 to [b][p][ic] bf16 hi/lo
        int p = i1 & (HW - 1);
        int b = i1 >> 14;
        const float* xp = x1 + (size_t)b * C * HW + p;
        bfx8 vh[8], vl[8];
#pragma unroll
        for (int k = 0; k < 8; ++k) {
#pragma unroll
            for (int j = 0; j < 8; ++j) {
                float x = xp[(size_t)(k * 8 + j) * HW];
                __hip_bfloat16 hb = __float2bfloat16(x);
                float hf = __bfloat162float(hb);
                __hip_bfloat16 lb = __float2bfloat16(x - hf);
                vh[k][j] = *(short*)&hb;
                vl[k][j] = *(short*)&lb;
            }
        }
        u16* dh = x1T_hi + (size_t)i1 * C;
        u16* dl = x1T_lo + (size_t)i1 * C;
#pragma unroll
        for (int k = 0; k < 8; ++k) {
            *(bfx8*)(dh + k * 8) = vh[k];
            *(bfx8*)(dl + k * 8) = vl[k];
        }
        return;
    }
    int i2 = i1 - B * HW;
    if (i2 < WB_N) {
        int step = i2 / STEP_E;
        int r    = i2 - step * STEP_E;
        int nfh  = r >> 10;          // 0..13
        int wsel = (r >> 9) & 1;     // 0=hi, 1=lo
        int lane = (r >> 3) & 63;
        int j    = r & 7;
        int t = step >> 1, chunk = step & 1;
        int ic = chunk * 32 + ((lane >> 4) << 3) + j;
        int oc = (nfh << 4) + (lane & 15);
        float v = (oc < OM_C) ? w_om[oc * (C * KK) + ic * KK + t] : 0.0f;
        __hip_bfloat16 hb = __float2bfloat16(v);
        if (wsel == 0) {
            wB[i2] = *(u16*)&hb;
        } else {
            float hf = __bfloat162float(hb);
            __hip_bfloat16 lb = __float2bfloat16(v - hf);
            wB[i2] = *(u16*)&lb;
        }
    }
}

// ---------------- prep2: x0 channel-interleave ----------------
__global__ void __launch_bounds__(256)
prep2_kernel(const float* __restrict__ x0, float* __restrict__ x0T) {
    int idx = blockIdx.x * 256 + threadIdx.x;
    int p  = idx & (HW - 1);
    int ch = (idx >> 14) & (C - 1);
    int b  = idx >> 20;
    x0T[((size_t)((b * DG + (ch >> 3)) * HW + p) << 3) + (ch & 7)] = x0[idx];
}

// ---------------- conv_offset_mask: pipelined LDS-staged MFMA ----------------
// Block = 256 thr = 4 waves = 2 wrow x 2 wcol. Wave tile M=64 px x N=112 oc,
// full K (18 tc-steps). B-slabs double-buffered in LDS via global_load_lds
// (28 KB/step); A fragments register-prefetched one step ahead.
__device__ __forceinline__ void stage_b(const u16* __restrict__ src,
                                        u16* dst, int tid) {
#pragma unroll
    for (int k = 0; k < 7; ++k) {
        __builtin_amdgcn_global_load_lds(
            (const __attribute__((address_space(1))) u16*)(src + k * 2048 + tid * 8),
            (__attribute__((address_space(3))) u16*)(dst + k * 2048 + tid * 8),
            16, 0, 0);
    }
}

__device__ __forceinline__ void load_a(const u16* __restrict__ xh_b,
                                       const u16* __restrict__ xl_b,
                                       int prow, int klane, int tcn,
                                       bfx8* ah, bfx8* al) {
    int t = tcn >> 1, chunk = tcn & 1;
    int ty = t / 3;
    int dy = ty - 1, dx = (t - ty * 3) - 1;
    const bfx8 bz = {0, 0, 0, 0, 0, 0, 0, 0};
#pragma unroll
    for (int mf = 0; mf < 4; ++mf) {
        int p  = prow + mf * 16;
        int hh = (p >> 7) + dy;
        int ww = (p & (W - 1)) + dx;
        bool vv = ((unsigned)hh < (unsigned)H) && ((unsigned)ww < (unsigned)W);
        int ch = min(max(hh, 0), H - 1);
        int cw = min(max(ww, 0), W - 1);
        size_t off = (size_t)((ch << 7) + cw) * C + chunk * 32 + klane;
        bfx8 zh = *(const bfx8*)(xh_b + off);
        bfx8 zl = *(const bfx8*)(xl_b + off);
        ah[mf] = vv ? zh : bz;
        al[mf] = vv ? zl : bz;
    }
}

__global__ void __launch_bounds__(256, 2)
conv_om_mfma_kernel(const u16* __restrict__ x1T_hi,
                    const u16* __restrict__ x1T_lo,
                    const u16* __restrict__ wB,
                    const float* __restrict__ b_om,
                    const float* __restrict__ pre_offset,
                    const float* __restrict__ pre_sim,
                    float* __restrict__ offset,
                    float* __restrict__ mask) {
    __shared__ u16 bbuf[2][STEP_E];   // 2 x 28672 B = 56 KB

    int bid  = blockIdx.x;                       // 256 blocks
    int work = ((bid & 7) << 5) + (bid >> 3);    // XCD-chunked
    int b    = work >> 7;
    int px0  = (work & 127) << 7;                // 128-px row tile

    int tid  = threadIdx.x;
    int lane = tid & 63;
    int wid  = tid >> 6;
    int wcol = wid & 1;
    int wrow = wid >> 1;

    fx4 acc[4][7];
#pragma unroll
    for (int mf = 0; mf < 4; ++mf)
#pragma unroll
        for (int nf = 0; nf < 7; ++nf) acc[mf][nf] = fx4{0.f, 0.f, 0.f, 0.f};

    int prow  = px0 + wrow * 64 + (lane & 15);   // + mf*16
    int klane = (lane >> 4) << 3;

    const u16* xh_b = x1T_hi + (size_t)b * HW * C;
    const u16* xl_b = x1T_lo + (size_t)b * HW * C;

    bfx8 ahn[4], aln[4];
    stage_b(wB, &bbuf[0][0], tid);
    load_a(xh_b, xl_b, prow, klane, 0, ahn, aln);
    __syncthreads();

#pragma unroll
    for (int tc = 0; tc < 18; ++tc) {
        bfx8 ahc[4], alc[4];
#pragma unroll
        for (int mf = 0; mf < 4; ++mf) { ahc[mf] = ahn[mf]; alc[mf] = aln[mf]; }
        if (tc < 17) {
            stage_b(wB + (size_t)(tc + 1) * STEP_E, &bbuf[(tc + 1) & 1][0], tid);
            load_a(xh_b, xl_b, prow, klane, tc + 1, ahn, aln);
        }
        const u16* bb = &bbuf[tc & 1][0];
#pragma unroll
        for (int nf = 0; nf < 7; ++nf) {
            const u16* bp = bb + (((wcol * 7 + nf) << 10) + (lane << 3));
            bfx8 bh = *(const bfx8*)bp;
            bfx8 bl = *(const bfx8*)(bp + 512);
#pragma unroll
            for (int mf = 0; mf < 4; ++mf) {
                acc[mf][nf] = __builtin_amdgcn_mfma_f32_16x16x32_bf16(ahc[mf], bh, acc[mf][nf], 0, 0, 0);
                acc[mf][nf] = __builtin_amdgcn_mfma_f32_16x16x32_bf16(alc[mf], bh, acc[mf][nf], 0, 0, 0);
                acc[mf][nf] = __builtin_amdgcn_mfma_f32_16x16x32_bf16(ahc[mf], bl, acc[mf][nf], 0, 0, 0);
            }
        }
        __syncthreads();
    }

    // Epilogue from fragment layout: col(oc)=lane&15, row(pix)=(lane>>4)*4+r.
#pragma unroll
    for (int mf = 0; mf < 4; ++mf) {
#pragma unroll
        for (int nf = 0; nf < 7; ++nf) {
            fx4 v = acc[mf][nf];
            int oc  = wcol * 112 + nf * 16 + (lane & 15);
            int pix = px0 + wrow * 64 + mf * 16 + ((lane >> 4) << 2);
            if (oc < OM_C) {
                float bb = b_om[oc];
                if (oc < OFF_C) {
                    size_t oi = (size_t)(b * OFF_C + oc) * HW + pix;
                    float4 po = *(const float4*)&pre_offset[oi];
                    float4 r;
                    r.x = MRM * tanhf(v[0] + bb) + po.x;
                    r.y = MRM * tanhf(v[1] + bb) + po.y;
                    r.z = MRM * tanhf(v[2] + bb) + po.z;
                    r.w = MRM * tanhf(v[3] + bb) + po.w;
                    *(float4*)&offset[oi] = r;
                } else {
                    size_t mi = (size_t)(b * MSK_C + oc - OFF_C) * HW + pix;
                    float4 ps = *(const float4*)&pre_sim[mi];
                    float4 r;
                    r.x = 1.0f / (1.0f + expf(-(v[0] + bb) * ps.x));
                    r.y = 1.0f / (1.0f + expf(-(v[1] + bb) * ps.y));
                    r.z = 1.0f / (1.0f + expf(-(v[2] + bb) * ps.z));
                    r.w = 1.0f / (1.0f + expf(-(v[3] + bb) * ps.w));
                    *(float4*)&mask[mi] = r;
                }
            }
        }
    }
}

// ---------------- Kernel: modulated deformable conv -----------------------
__global__ void __launch_bounds__(512, 4)
deform_conv_kernel(const float* __restrict__ x0T,
                   const float* __restrict__ offset,
                   const float* __restrict__ mask,
                   const float* __restrict__ wT,
                   const float* __restrict__ bias,
                   float* __restrict__ out) {
    __shared__ float red[8 * 64 * 9];   // 18 KB

    int work  = xcd_work(blockIdx.x);
    int pbase = (work & 255) * 64;
    int b     = work >> 8;

    int tid  = threadIdx.x;
    int lane = tid & 63;
    int g    = __builtin_amdgcn_readfirstlane(tid >> 6);  // wave-uniform
    int p = pbase + lane;
    int h = p >> 7;
    int w = p & (W - 1);

    float acc[O];
#pragma unroll
    for (int o = 0; o < O; ++o) acc[o] = 0.0f;

    const float* offb = offset + (size_t)b * OFF_C * HW + p;
    const float* mb   = mask + (size_t)b * MSK_C * HW + p;
    const float* xg   = x0T + ((size_t)(b * DG + g) * HW) * CG;

    for (int i = 0; i < KK; ++i) {
        int gi = g * KK + i;
        float offy = offb[(2 * gi) * HW];
        float offx = offb[(2 * gi + 1) * HW];
        float m    = mb[gi * HW];

        float py = offy + (float)(h - 1 + i / 3);
        float px = offx + (float)(w - 1 + i % 3);
        float fy = floorf(py), fx = floorf(px);
        float ly = py - fy, lx = px - fx;
        float hy = 1.0f - ly, hx = 1.0f - lx;
        int y0 = (int)fy, x0i = (int)fx;
        int y1 = y0 + 1, x1i = x0i + 1;
        bool vy0 = (y0 >= 0) && (y0 < H);
        bool vy1 = (y1 >= 0) && (y1 < H);
        bool vx0 = (x0i >= 0) && (x0i < W);
        bool vx1 = (x1i >= 0) && (x1i < W);
        int cy0 = min(max(y0, 0), H - 1), cy1 = min(max(y1, 0), H - 1);
        int cx0 = min(max(x0i, 0), W - 1), cx1 = min(max(x1i, 0), W - 1);
        float w00 = hy * hx * ((vy0 && vx0) ? 1.0f : 0.0f) * m;
        float w01 = hy * lx * ((vy0 && vx1) ? 1.0f : 0.0f) * m;
        float w10 = ly * hx * ((vy1 && vx0) ? 1.0f : 0.0f) * m;
        float w11 = ly * lx * ((vy1 && vx1) ? 1.0f : 0.0f) * m;
        int i00 = cy0 * W + cx0, i01 = cy0 * W + cx1;
        int i10 = cy1 * W + cx0, i11 = cy1 * W + cx1;

        const float4* A  = (const float4*)(xg + (size_t)i00 * CG);
        const float4* Bc = (const float4*)(xg + (size_t)i01 * CG);
        const float4* Cc = (const float4*)(xg + (size_t)i10 * CG);
        const float4* Dc = (const float4*)(xg + (size_t)i11 * CG);
        float4 a0 = A[0],  a1 = A[1];
        float4 b0 = Bc[0], b1 = Bc[1];
        float4 c0 = Cc[0], c1 = Cc[1];
        float4 d0 = Dc[0], d1 = Dc[1];

        float v[CG];
        v[0] = w00 * a0.x + w01 * b0.x + w10 * c0.x + w11 * d0.x;
        v[1] = w00 * a0.y + w01 * b0.y + w10 * c0.y + w11 * d0.y;
        v[2] = w00 * a0.z + w01 * b0.z + w10 * c0.z + w11 * d0.z;
        v[3] = w00 * a0.w + w01 * b0.w + w10 * c0.w + w11 * d0.w;
        v[4] = w00 * a1.x + w01 * b1.x + w10 * c1.x + w11 * d1.x;
        v[5] = w00 * a1.y + w01 * b1.y + w10 * c1.y + w11 * d1.y;
        v[6] = w00 * a1.z + w01 * b1.z + w10 * c1.z + w11 * d1.z;
        v[7] = w00 * a1.w + w01 * b1.w + w10 * c1.w + w11 * d1.w;

        const float* wrow = wT + (size_t)(gi * CG) * O;   // wave-uniform
#pragma unroll
        for (int c = 0; c < CG; ++c) {
#pragma unroll
            for (int o = 0; o < O; ++o)
                acc[o] = fmaf(v[c], wrow[c * O + o], acc[o]);
        }
    }

    // Cross-group reduction: 8 chunks of 8 output channels.
    int ocp = tid >> 6;
#pragma unroll
    for (int chunk = 0; chunk < 8; ++chunk) {
        float* slot = &red[(g * 64 + lane) * 9];
#pragma unroll
        for (int j = 0; j < 8; ++j) slot[j] = acc[chunk * 8 + j];
        __syncthreads();
        float s = 0.0f;
#pragma unroll
        for (int wv = 0; wv < 8; ++wv) s += red[(wv * 64 + lane) * 9 + ocp];
        int oc = chunk * 8 + ocp;
        out[((size_t)b * O + oc) * HW + pbase + lane] = s + bias[oc];
        __syncthreads();
    }
}

// ---------------- Launch ----------------
extern "C" void kernel_launch(void* const* d_in, const int* in_sizes, int n_in,
                              void* d_out, int out_size, void* d_ws, size_t ws_size,
                              hipStream_t stream) {
    (void)in_sizes; (void)n_in; (void)out_size; (void)ws_size;
    const float* x0         = (const float*)d_in[0];
    const float* x1         = (const float*)d_in[1];
    const float* pre_offset = (const float*)d_in[2];
    const float* pre_sim    = (const float*)d_in[3];
    const float* weight     = (const float*)d_in[4];
    const float* bias       = (const float*)d_in[5];
    const float* w_om       = (const float*)d_in[6];
    const float* b_om       = (const float*)d_in[7];
    float* out = (float*)d_out;

    // ws layout (floats):
    float* offset = (float*)d_ws;                       // B*144*HW
    float* mask   = offset + (size_t)B * OFF_C * HW;    // B*72*HW
    float* wT     = mask + (size_t)B * MSK_C * HW;      // 36864
    float* xbuf   = wT + WT_N;                          // union region (2097152 floats)
    u16*   x1T_hi = (u16*)xbuf;                         // B*HW*C bf16
    u16*   x1T_lo = x1T_hi + (size_t)B * HW * C;        // B*HW*C bf16
    float* x0T    = xbuf;                               // reuses x1T region (after conv)
    u16*   wB     = (u16*)(xbuf + X0T_N);               // 258048 bf16

    {
        int total = WT_N + B * HW + WB_N;   // 327680
        prep1_kernel<<<total / 256, 256, 0, stream>>>(
            weight, w_om, x1, wT, x1T_hi, x1T_lo, wB);
    }
    {
        conv_om_mfma_kernel<<<256, 256, 0, stream>>>(
            x1T_hi, x1T_lo, wB, b_om, pre_offset, pre_sim, offset, mask);
    }
    {
        prep2_kernel<<<X0T_N / 256, 256, 0, stream>>>(x0, x0T);
    }
    {
        deform_conv_kernel<<<512, 512, 0, stream>>>(
            x0T, offset, mask, wT, bias, out);
    }
}

// Round 9
// 106.444 us; speedup vs baseline: 1.1037x; 1.1037x over previous
//
#include <hip/hip_runtime.h>
#include <hip/hip_bf16.h>
#include <math.h>

// Problem constants
constexpr int B  = 2;
constexpr int C  = 64;
constexpr int H  = 128;
constexpr int W  = 128;
constexpr int O  = 64;
constexpr int DG = 8;
constexpr int K  = 3;
constexpr int KK = K * K;           // 9
constexpr int HW = H * W;           // 16384
constexpr int CG = C / DG;          // 8
constexpr int OM_C  = 3 * DG * KK;  // 216
constexpr int OFF_C = 2 * DG * KK;  // 144
constexpr int MSK_C = DG * KK;      // 72
constexpr float MRM = 10.0f;

typedef unsigned short u16;
typedef short bfx8 __attribute__((ext_vector_type(8)));   // 8 bf16 (4 VGPRs)
typedef float fx4 __attribute__((ext_vector_type(4)));    // MFMA accumulator

// Sizes
constexpr int WT_N   = 576 * 64;        // deform weights, transposed
constexpr int X0T_N  = B * C * HW;      // 2097152 floats (x0 interleaved)
constexpr int STEP_E = 14336;           // u16 per tc-step slab (28 KB)
constexpr int WB_N   = 18 * STEP_E;     // 258048

// XCD chunk swizzle (512 blocks): XCD x gets 64 consecutive works.
__device__ __forceinline__ int xcd_work(int bid) {
    return ((bid & 7) << 6) + (bid >> 3);
}

// ---------------- prep1: wT (deform), x1T hi/lo (pixel-major bf16), wB ----
// wB layout (u16): [step 18][nfh 14][wsel 2][lane 64][j 8]
//   step = t*2+chunk; ic = chunk*32 + (lane>>4)*8 + j; oc = nfh*16 + (lane&15)
__global__ void __launch_bounds__(256)
prep1_kernel(const float* __restrict__ weight,
             const float* __restrict__ w_om,
             const float* __restrict__ x1,
             float* __restrict__ wT,
             u16* __restrict__ x1T_hi,
             u16* __restrict__ x1T_lo,
             u16* __restrict__ wB) {
    int idx = blockIdx.x * 256 + threadIdx.x;
    if (idx < WT_N) {
        int r = idx / O;          // (g*KK+i)*CG + c
        int o = idx - r * O;
        int g = r / (KK * CG);
        int rem = r - g * (KK * CG);
        int i = rem / CG;
        int c = rem - i * CG;
        wT[idx] = weight[o * (C * KK) + (g * CG + c) * KK + i];
        return;
    }
    int i1 = idx - WT_N;
    if (i1 < B * HW) {   // one thread per (b,p): transpose x1 to [b][p][ic] bf16 hi/lo
        int p = i1 & (HW - 1);
        int b = i1 >> 14;
        const float* xp = x1 + (size_t)b * C * HW + p;
        bfx8 vh[8], vl[8];
#pragma unroll
        for (int k = 0; k < 8; ++k) {
#pragma unroll
            for (int j = 0; j < 8; ++j) {
                float x = xp[(size_t)(k * 8 + j) * HW];
                __hip_bfloat16 hb = __float2bfloat16(x);
                float hf = __bfloat162float(hb);
                __hip_bfloat16 lb = __float2bfloat16(x - hf);
                vh[k][j] = *(short*)&hb;
                vl[k][j] = *(short*)&lb;
            }
        }
        u16* dh = x1T_hi + (size_t)i1 * C;
        u16* dl = x1T_lo + (size_t)i1 * C;
#pragma unroll
        for (int k = 0; k < 8; ++k) {
            *(bfx8*)(dh + k * 8) = vh[k];
            *(bfx8*)(dl + k * 8) = vl[k];
        }
        return;
    }
    int i2 = i1 - B * HW;
    if (i2 < WB_N) {
        int step = i2 / STEP_E;
        int r    = i2 - step * STEP_E;
        int nfh  = r >> 10;          // 0..13
        int wsel = (r >> 9) & 1;     // 0=hi, 1=lo
        int lane = (r >> 3) & 63;
        int j    = r & 7;
        int t = step >> 1, chunk = step & 1;
        int ic = chunk * 32 + ((lane >> 4) << 3) + j;
        int oc = (nfh << 4) + (lane & 15);
        float v = (oc < OM_C) ? w_om[oc * (C * KK) + ic * KK + t] : 0.0f;
        __hip_bfloat16 hb = __float2bfloat16(v);
        if (wsel == 0) {
            wB[i2] = *(u16*)&hb;
        } else {
            float hf = __bfloat162float(hb);
            __hip_bfloat16 lb = __float2bfloat16(v - hf);
            wB[i2] = *(u16*)&lb;
        }
    }
}

// ---------------- prep2: x0 channel-interleave ----------------
__global__ void __launch_bounds__(256)
prep2_kernel(const float* __restrict__ x0, float* __restrict__ x0T) {
    int idx = blockIdx.x * 256 + threadIdx.x;
    int p  = idx & (HW - 1);
    int ch = (idx >> 14) & (C - 1);
    int b  = idx >> 20;
    x0T[((size_t)((b * DG + (ch >> 3)) * HW + p) << 3) + (ch & 7)] = x0[idx];
}

// ---------------- conv_offset_mask: block-shared LDS B, 16 waves ----------
// Block = 1024 thr = 16 waves = 4 wrow x 2 wcol x 2 kid. Wave tile M=32 px x
// N=112 oc, K = 9 tc-steps per kid. B slabs for both kids double-buffered in
// LDS (2 x 2 x 28 KB = 112 KB), staged once per block per step by 14 waves
// via global_load_lds; ds_read_b128 feeds MFMA. A register-prefetched.
// After the K-loop the LDS is reused as the kid-reduction buffer (8 slots).
__device__ __forceinline__ void load_a2(const u16* __restrict__ xh_b,
                                        const u16* __restrict__ xl_b,
                                        int prow, int klane, int tcn,
                                        bfx8* ah, bfx8* al) {
    int t = tcn >> 1, chunk = tcn & 1;
    int ty = t / 3;
    int dy = ty - 1, dx = (t - ty * 3) - 1;
    const bfx8 bz = {0, 0, 0, 0, 0, 0, 0, 0};
#pragma unroll
    for (int mf = 0; mf < 2; ++mf) {
        int p  = prow + mf * 16;
        int hh = (p >> 7) + dy;
        int ww = (p & (W - 1)) + dx;
        bool vv = ((unsigned)hh < (unsigned)H) && ((unsigned)ww < (unsigned)W);
        int ch = min(max(hh, 0), H - 1);
        int cw = min(max(ww, 0), W - 1);
        size_t off = (size_t)((ch << 7) + cw) * C + chunk * 32 + klane;
        bfx8 zh = *(const bfx8*)(xh_b + off);
        bfx8 zl = *(const bfx8*)(xl_b + off);
        ah[mf] = vv ? zh : bz;
        al[mf] = vv ? zl : bz;
    }
}

__global__ void __launch_bounds__(1024, 4)
conv_om_mfma_kernel(const u16* __restrict__ x1T_hi,
                    const u16* __restrict__ x1T_lo,
                    const u16* __restrict__ wB,
                    const float* __restrict__ b_om,
                    const float* __restrict__ pre_offset,
                    const float* __restrict__ pre_sim,
                    float* __restrict__ offset,
                    float* __restrict__ mask) {
    __shared__ __align__(16) u16 smem[2][2][STEP_E];   // 112 KB

    int work = blockIdx.x;           // 256 blocks
    int b    = work >> 7;
    int px0  = (work & 127) << 7;    // 128-px tile

    int tid  = threadIdx.x;
    int lane = tid & 63;
    int wid  = tid >> 6;             // 0..15
    int kid  = wid & 1;
    int wcol = (wid >> 1) & 1;
    int wrow = wid >> 2;             // 0..3

    fx4 acc[2][7];
#pragma unroll
    for (int mf = 0; mf < 2; ++mf)
#pragma unroll
        for (int nf = 0; nf < 7; ++nf) acc[mf][nf] = fx4{0.f, 0.f, 0.f, 0.f};

    int prow  = px0 + wrow * 32 + (lane & 15);   // + mf*16
    int klane = (lane >> 4) << 3;

    const u16* xh_b = x1T_hi + (size_t)b * HW * C;
    const u16* xl_b = x1T_lo + (size_t)b * HW * C;

    // staging role: waves 0..6 -> kid0 slab chunks, 7..13 -> kid1 slab chunks
    bool stager = (wid < 14);
    int  skid   = (wid >= 7) ? 1 : 0;
    int  scw    = skid ? (wid - 7) : wid;       // 0..6
    int  soff   = scw * 2048 + lane * 8;        // u16 offset within slab

    // prologue: stage phase-0 slabs (steps 0 and 9) into smem[0]
    if (stager) {
        const u16* s = wB + (size_t)(skid * 9) * STEP_E + soff;
        u16* d = &smem[0][skid][soff];
#pragma unroll
        for (int k = 0; k < 4; ++k) {
            __builtin_amdgcn_global_load_lds(
                (const __attribute__((address_space(1))) u16*)(s + k * 512),
                (__attribute__((address_space(3))) u16*)(d + k * 512),
                16, 0, 0);
        }
    }
    bfx8 ahc[2], alc[2], ahn[2], aln[2];
    load_a2(xh_b, xl_b, prow, klane, kid * 9, ahc, alc);
    __syncthreads();

#pragma unroll
    for (int j = 0; j < 9; ++j) {
        if (j < 8) {
            if (stager) {
                const u16* s = wB + (size_t)(skid * 9 + j + 1) * STEP_E + soff;
                u16* d = &smem[(j + 1) & 1][skid][soff];
#pragma unroll
                for (int k = 0; k < 4; ++k) {
                    __builtin_amdgcn_global_load_lds(
                        (const __attribute__((address_space(1))) u16*)(s + k * 512),
                        (__attribute__((address_space(3))) u16*)(d + k * 512),
                        16, 0, 0);
                }
            }
            load_a2(xh_b, xl_b, prow, klane, kid * 9 + j + 1, ahn, aln);
        }
        const u16* slab = &smem[j & 1][kid][0];
#pragma unroll
        for (int nf = 0; nf < 7; ++nf) {
            const u16* bp = slab + (((wcol * 7 + nf) << 10) + (lane << 3));
            bfx8 bh = *(const bfx8*)bp;
            bfx8 bl = *(const bfx8*)(bp + 512);
#pragma unroll
            for (int mf = 0; mf < 2; ++mf) {
                acc[mf][nf] = __builtin_amdgcn_mfma_f32_16x16x32_bf16(ahc[mf], bh, acc[mf][nf], 0, 0, 0);
                acc[mf][nf] = __builtin_amdgcn_mfma_f32_16x16x32_bf16(alc[mf], bh, acc[mf][nf], 0, 0, 0);
                acc[mf][nf] = __builtin_amdgcn_mfma_f32_16x16x32_bf16(ahc[mf], bl, acc[mf][nf], 0, 0, 0);
            }
        }
        __syncthreads();
        if (j < 8) {
#pragma unroll
            for (int mf = 0; mf < 2; ++mf) { ahc[mf] = ahn[mf]; alc[mf] = aln[mf]; }
        }
    }

    // kid reduction through LDS (reuse smem as 8-slot fx4 buffer).
    fx4* red = (fx4*)&smem[0][0][0];
    int slot = wrow * 2 + wcol;      // 0..7
    if (kid) {
#pragma unroll
        for (int mf = 0; mf < 2; ++mf)
#pragma unroll
            for (int nf = 0; nf < 7; ++nf)
                red[(slot * 14 + mf * 7 + nf) * 64 + lane] = acc[mf][nf];
    }
    __syncthreads();
    if (!kid) {
        // Epilogue from fragment layout: col(oc)=lane&15, row(pix)=(lane>>4)*4+r.
#pragma unroll
        for (int mf = 0; mf < 2; ++mf) {
#pragma unroll
            for (int nf = 0; nf < 7; ++nf) {
                fx4 v = acc[mf][nf] + red[(slot * 14 + mf * 7 + nf) * 64 + lane];
                int oc  = wcol * 112 + nf * 16 + (lane & 15);
                int pix = px0 + wrow * 32 + mf * 16 + ((lane >> 4) << 2);
                if (oc < OM_C) {
                    float bb = b_om[oc];
                    if (oc < OFF_C) {
                        size_t oi = (size_t)(b * OFF_C + oc) * HW + pix;
                        float4 po = *(const float4*)&pre_offset[oi];
                        float4 r;
                        r.x = MRM * tanhf(v[0] + bb) + po.x;
                        r.y = MRM * tanhf(v[1] + bb) + po.y;
                        r.z = MRM * tanhf(v[2] + bb) + po.z;
                        r.w = MRM * tanhf(v[3] + bb) + po.w;
                        *(float4*)&offset[oi] = r;
                    } else {
                        size_t mi = (size_t)(b * MSK_C + oc - OFF_C) * HW + pix;
                        float4 ps = *(const float4*)&pre_sim[mi];
                        float4 r;
                        r.x = 1.0f / (1.0f + expf(-(v[0] + bb) * ps.x));
                        r.y = 1.0f / (1.0f + expf(-(v[1] + bb) * ps.y));
                        r.z = 1.0f / (1.0f + expf(-(v[2] + bb) * ps.z));
                        r.w = 1.0f / (1.0f + expf(-(v[3] + bb) * ps.w));
                        *(float4*)&mask[mi] = r;
                    }
                }
            }
        }
    }
}

// ---------------- Kernel: modulated deformable conv -----------------------
__global__ void __launch_bounds__(512, 4)
deform_conv_kernel(const float* __restrict__ x0T,
                   const float* __restrict__ offset,
                   const float* __restrict__ mask,
                   const float* __restrict__ wT,
                   const float* __restrict__ bias,
                   float* __restrict__ out) {
    __shared__ float red[8 * 64 * 9];   // 18 KB

    int work  = xcd_work(blockIdx.x);
    int pbase = (work & 255) * 64;
    int b     = work >> 8;

    int tid  = threadIdx.x;
    int lane = tid & 63;
    int g    = __builtin_amdgcn_readfirstlane(tid >> 6);  // wave-uniform
    int p = pbase + lane;
    int h = p >> 7;
    int w = p & (W - 1);

    float acc[O];
#pragma unroll
    for (int o = 0; o < O; ++o) acc[o] = 0.0f;

    const float* offb = offset + (size_t)b * OFF_C * HW + p;
    const float* mb   = mask + (size_t)b * MSK_C * HW + p;
    const float* xg   = x0T + ((size_t)(b * DG + g) * HW) * CG;

    for (int i = 0; i < KK; ++i) {
        int gi = g * KK + i;
        float offy = offb[(2 * gi) * HW];
        float offx = offb[(2 * gi + 1) * HW];
        float m    = mb[gi * HW];

        float py = offy + (float)(h - 1 + i / 3);
        float px = offx + (float)(w - 1 + i % 3);
        float fy = floorf(py), fx = floorf(px);
        float ly = py - fy, lx = px - fx;
        float hy = 1.0f - ly, hx = 1.0f - lx;
        int y0 = (int)fy, x0i = (int)fx;
        int y1 = y0 + 1, x1i = x0i + 1;
        bool vy0 = (y0 >= 0) && (y0 < H);
        bool vy1 = (y1 >= 0) && (y1 < H);
        bool vx0 = (x0i >= 0) && (x0i < W);
        bool vx1 = (x1i >= 0) && (x1i < W);
        int cy0 = min(max(y0, 0), H - 1), cy1 = min(max(y1, 0), H - 1);
        int cx0 = min(max(x0i, 0), W - 1), cx1 = min(max(x1i, 0), W - 1);
        float w00 = hy * hx * ((vy0 && vx0) ? 1.0f : 0.0f) * m;
        float w01 = hy * lx * ((vy0 && vx1) ? 1.0f : 0.0f) * m;
        float w10 = ly * hx * ((vy1 && vx0) ? 1.0f : 0.0f) * m;
        float w11 = ly * lx * ((vy1 && vx1) ? 1.0f : 0.0f) * m;
        int i00 = cy0 * W + cx0, i01 = cy0 * W + cx1;
        int i10 = cy1 * W + cx0, i11 = cy1 * W + cx1;

        const float4* A  = (const float4*)(xg + (size_t)i00 * CG);
        const float4* Bc = (const float4*)(xg + (size_t)i01 * CG);
        const float4* Cc = (const float4*)(xg + (size_t)i10 * CG);
        const float4* Dc = (const float4*)(xg + (size_t)i11 * CG);
        float4 a0 = A[0],  a1 = A[1];
        float4 b0 = Bc[0], b1 = Bc[1];
        float4 c0 = Cc[0], c1 = Cc[1];
        float4 d0 = Dc[0], d1 = Dc[1];

        float v[CG];
        v[0] = w00 * a0.x + w01 * b0.x + w10 * c0.x + w11 * d0.x;
        v[1] = w00 * a0.y + w01 * b0.y + w10 * c0.y + w11 * d0.y;
        v[2] = w00 * a0.z + w01 * b0.z + w10 * c0.z + w11 * d0.z;
        v[3] = w00 * a0.w + w01 * b0.w + w10 * c0.w + w11 * d0.w;
        v[4] = w00 * a1.x + w01 * b1.x + w10 * c1.x + w11 * d1.x;
        v[5] = w00 * a1.y + w01 * b1.y + w10 * c1.y + w11 * d1.y;
        v[6] = w00 * a1.z + w01 * b1.z + w10 * c1.z + w11 * d1.z;
        v[7] = w00 * a1.w + w01 * b1.w + w10 * c1.w + w11 * d1.w;

        const float* wrow = wT + (size_t)(gi * CG) * O;   // wave-uniform
#pragma unroll
        for (int c = 0; c < CG; ++c) {
#pragma unroll
            for (int o = 0; o < O; ++o)
                acc[o] = fmaf(v[c], wrow[c * O + o], acc[o]);
        }
    }

    // Cross-group reduction: 8 chunks of 8 output channels.
    int ocp = tid >> 6;
#pragma unroll
    for (int chunk = 0; chunk < 8; ++chunk) {
        float* slot = &red[(g * 64 + lane) * 9];
#pragma unroll
        for (int j = 0; j < 8; ++j) slot[j] = acc[chunk * 8 + j];
        __syncthreads();
        float s = 0.0f;
#pragma unroll
        for (int wv = 0; wv < 8; ++wv) s += red[(wv * 64 + lane) * 9 + ocp];
        int oc = chunk * 8 + ocp;
        out[((size_t)b * O + oc) * HW + pbase + lane] = s + bias[oc];
        __syncthreads();
    }
}

// ---------------- Launch ----------------
extern "C" void kernel_launch(void* const* d_in, const int* in_sizes, int n_in,
                              void* d_out, int out_size, void* d_ws, size_t ws_size,
                              hipStream_t stream) {
    (void)in_sizes; (void)n_in; (void)out_size; (void)ws_size;
    const float* x0         = (const float*)d_in[0];
    const float* x1         = (const float*)d_in[1];
    const float* pre_offset = (const float*)d_in[2];
    const float* pre_sim    = (const float*)d_in[3];
    const float* weight     = (const float*)d_in[4];
    const float* bias       = (const float*)d_in[5];
    const float* w_om       = (const float*)d_in[6];
    const float* b_om       = (const float*)d_in[7];
    float* out = (float*)d_out;

    // ws layout (floats):
    float* offset = (float*)d_ws;                       // B*144*HW
    float* mask   = offset + (size_t)B * OFF_C * HW;    // B*72*HW
    float* wT     = mask + (size_t)B * MSK_C * HW;      // 36864
    float* xbuf   = wT + WT_N;                          // union region (2097152 floats)
    u16*   x1T_hi = (u16*)xbuf;                         // B*HW*C bf16
    u16*   x1T_lo = x1T_hi + (size_t)B * HW * C;        // B*HW*C bf16
    float* x0T    = xbuf;                               // reuses x1T region (after conv)
    u16*   wB     = (u16*)(xbuf + X0T_N);               // 258048 bf16

    {
        int total = WT_N + B * HW + WB_N;   // 327680
        prep1_kernel<<<total / 256, 256, 0, stream>>>(
            weight, w_om, x1, wT, x1T_hi, x1T_lo, wB);
    }
    {
        conv_om_mfma_kernel<<<256, 1024, 0, stream>>>(
            x1T_hi, x1T_lo, wB, b_om, pre_offset, pre_sim, offset, mask);
    }
    {
        prep2_kernel<<<X0T_N / 256, 256, 0, stream>>>(x0, x0T);
    }
    {
        deform_conv_kernel<<<512, 512, 0, stream>>>(
            x0T, offset, mask, wT, bias, out);
    }
}